// Round 2
// baseline (153.704 us; speedup 1.0000x reference)
//
#include <hip/hip_runtime.h>

// Problem constants
#define B_  32
#define C_  64
#define H_  64
#define W_  64
#define O_  128
#define LAT 64
#define HW  (H_*W_)
#define KJ  (O_*C_*9)      // 73728
#define KTOT 576           // C_*9, GEMM K per batch
#define NKS 18             // K steps of 32

typedef __bf16 bf16x8 __attribute__((ext_vector_type(8)));
typedef float  f32x4  __attribute__((ext_vector_type(4)));

// ---------------------------------------------------------------------------
// Stage 1: transpose x -> xT[b][h][w][c] bf16, plus per-(b,h,c) row sums.
// ---------------------------------------------------------------------------
__global__ __launch_bounds__(256) void transpose_gap(const float* __restrict__ x,
                                                     __bf16* __restrict__ xT,
                                                     float* __restrict__ gap_part) {
    int bh = blockIdx.x, b = bh >> 6, h = bh & 63;
    __shared__ float lt[64 * 65];
    int t = threadIdx.x;
    int cc0 = t >> 4, w4 = (t & 15) * 4;

    #pragma unroll
    for (int i = 0; i < 4; i++) {
        int cc = cc0 + 16 * i;
        float4 v = *(const float4*)(x + (((size_t)(b * C_ + cc) * H_) + h) * W_ + w4);
        lt[cc * 65 + w4 + 0] = v.x;
        lt[cc * 65 + w4 + 1] = v.y;
        lt[cc * 65 + w4 + 2] = v.z;
        lt[cc * 65 + w4 + 3] = v.w;
        float s = (v.x + v.y) + (v.z + v.w);
        s += __shfl_xor(s, 1); s += __shfl_xor(s, 2);
        s += __shfl_xor(s, 4); s += __shfl_xor(s, 8);
        if ((t & 15) == 0) gap_part[h * 2048 + b * 64 + cc] = s;
    }
    __syncthreads();

    __bf16* dst = xT + ((size_t)(b * H_ + h) * W_) * C_;
    #pragma unroll
    for (int k = 0; k < 2; k++) {
        int chunk = t + k * 256;
        int w = chunk >> 3, c8 = chunk & 7;
        __bf16 g[8];
        #pragma unroll
        for (int i = 0; i < 8; i++) g[i] = (__bf16)lt[(c8 * 8 + i) * 65 + w];
        *(int4*)(dst + w * C_ + c8 * 8) = *(int4*)g;
    }
}

// ---------------------------------------------------------------------------
// Stage 2: gap reduction + MLP. Writes f2 TRANSPOSED: f2t[l][b] so kergen
// can read 16 consecutive per-b values with block-uniform s_loads.
// ---------------------------------------------------------------------------
__global__ __launch_bounds__(64) void mlp_kernel(const float* __restrict__ gap_part,
                                                 const float* __restrict__ W1,
                                                 const float* __restrict__ b1,
                                                 const float* __restrict__ W2,
                                                 const float* __restrict__ b2,
                                                 float* __restrict__ f2t) {
    int b = blockIdx.x, j = threadIdx.x;
    float s = 0.f;
    #pragma unroll 16
    for (int h = 0; h < 64; h++) s += gap_part[h * 2048 + b * 64 + j];
    __shared__ float g[LAT], f1[LAT];
    g[j] = s * (1.0f / (float)HW);
    __syncthreads();
    float acc = b1[j];
    #pragma unroll 8
    for (int l = 0; l < LAT; l++) acc = fmaf(g[l], W1[l * LAT + j], acc);
    f1[j] = fmaxf(acc, 0.f);
    __syncthreads();
    float acc2 = b2[j];
    #pragma unroll 8
    for (int l = 0; l < LAT; l++) acc2 = fmaf(f1[l], W2[l * LAT + j], acc2);
    f2t[j * B_ + b] = fmaxf(acc2, 0.f);       // transposed store
}

// ---------------------------------------------------------------------------
// Stage 3: kernel generator -> bf16, conv-native layout
//   kbf2[b][ks][o][kk],  ks = tap*2 + (c>=32), kk = c&31   (k = ks*32+kk)
// ---------------------------------------------------------------------------
#define KGP2 592
__global__ __launch_bounds__(576) void kergen_kernel(const float* __restrict__ f2t,
                                                     const float* __restrict__ Wf,
                                                     const float* __restrict__ bfv,
                                                     __bf16* __restrict__ kbf2) {
    int o = blockIdx.x & 127, b0 = (blockIdx.x >> 7) * 16;
    int t = threadIdx.x;
    __shared__ __bf16 ltk[16 * KGP2];          // 18.9 KB

    int j = o * KTOT + t;
    float acc[16];
    float base = bfv[j];
    #pragma unroll
    for (int i = 0; i < 16; i++) acc[i] = base;

    for (int l8 = 0; l8 < LAT; l8 += 8) {
        float w8[8];
        #pragma unroll
        for (int i = 0; i < 8; i++) w8[i] = Wf[(size_t)(l8 + i) * KJ + j];
        #pragma unroll
        for (int i = 0; i < 8; i++) {
            #pragma unroll
            for (int bb = 0; bb < 16; bb++)
                acc[bb] = fmaf(f2t[(l8 + i) * B_ + b0 + bb], w8[i], acc[bb]);
        }
    }

    int c = t / 9, tap = t - c * 9;
    int tpp = (tap * 2 + (c >> 5)) * 32 + (c & 31);
    #pragma unroll
    for (int bb = 0; bb < 16; bb++) ltk[bb * KGP2 + tpp] = (__bf16)acc[bb];
    __syncthreads();
    int ks = t >> 5, kk = t & 31;
    #pragma unroll
    for (int bb = 0; bb < 16; bb++)
        kbf2[(((size_t)(b0 + bb) * NKS + ks) * O_ + o) * 32 + kk] = ltk[bb * KGP2 + t];
}

// ---------------------------------------------------------------------------
// Stage 4: implicit-GEMM MFMA conv. M=128 o, N=128 px (2 rows), K=576.
// ROUND-2 CHANGE: per-wave register demand with 256-thread blocks is
// structurally 64 acc + 32 Abuf + ~40 misc > the 128-reg cap that 4 waves/
// SIMD imposes -> round-1's (256,4) spilled and gained only ~6us. Fix by
// changing thread geometry, not prefetch: 512-thread blocks (8 waves) on
// the SAME 128x128 tile. Per wave: M32xN64 -> acc[2][4]=32 regs,
// Abuf[2][2]=16 regs, total ~90 << 128 cap of __launch_bounds__(512,4).
// No spill possible. M32xN64 (not M64xN32) keeps the A-load/MFMA byte ratio
// at round-1's 52 B/cyc/CU (<= L1 64 B/cyc); LDS read rate 103 <= 128 B/cyc.
// 2 blocks/CU (LDS 75 KB, 16 waves) -> grid 1024 runs as TWO generations:
// gen-2 staging overlaps gen-1's 64 MB epilogue write burst.
// XCD swizzle: htile = (bx&7)*4 + (bx>>3) keeps halo rows L2-local.
// ---------------------------------------------------------------------------
#define CPAD 72
#define ROWE (66 * CPAD)

__global__ __launch_bounds__(512, 4) void conv_mfma(const __bf16* __restrict__ xT,
                                                    const __bf16* __restrict__ kbf2,
                                                    float* __restrict__ out) {
    int b  = blockIdx.y;
    int bx = blockIdx.x;
    int htile = (bx & 7) * 4 + (bx >> 3);      // XCD-local h-tile grouping
    int h0 = htile * 2;
    __shared__ __bf16 xs[4 * ROWE];
    int tid = threadIdx.x;

    // zero halo columns w'=0 and w'=65
    if (tid < 64) {
        int r = tid >> 4, which = (tid >> 3) & 1, c8 = tid & 7;
        *(int4*)(xs + (r * 66 + which * 65) * CPAD + c8 * 8) = int4{0, 0, 0, 0};
    }
    // zero OOB rows (edge blocks only)
    if (h0 == 0) {
        for (int i = tid; i < ROWE / 8; i += 512)
            *(int4*)(xs + i * 8) = int4{0, 0, 0, 0};
    }
    if (h0 == H_ - 2) {
        for (int i = tid; i < ROWE / 8; i += 512)
            *(int4*)(xs + 3 * ROWE + i * 8) = int4{0, 0, 0, 0};
    }

    // stage rows h0-1 .. h0+2 (2048 int4 chunks over 512 threads)
    #pragma unroll
    for (int i = 0; i < 4; i++) {
        int chunk = tid + i * 512;
        int c8 = chunk & 7, w = (chunk >> 3) & 63, r = chunk >> 9;
        int hh = h0 - 1 + r;
        if ((unsigned)hh < (unsigned)H_) {
            int4 v = *(const int4*)(xT + ((size_t)(b * H_ + hh) * W_ + w) * C_ + c8 * 8);
            *(int4*)(xs + (r * 66 + w + 1) * CPAD + c8 * 8) = v;
        }
    }
    __syncthreads();

    int wave = tid >> 6, lane = tid & 63;
    int wi = wave >> 1, wj = wave & 1;         // wi: M 4x32, wj: h row
    int l15 = lane & 15, quad = lane >> 4;

    const __bf16* kbA = kbf2 + (size_t)b * (NKS * O_ * 32);
    int mrow = wi * 32 + l15;                  // +mt*16, mt<2

    f32x4 acc[2][4];
    #pragma unroll
    for (int mt = 0; mt < 2; mt++)
        #pragma unroll
        for (int nt = 0; nt < 4; nt++)
            acc[mt][nt] = (f32x4){0.f, 0.f, 0.f, 0.f};

    bf16x8 Abuf[2][2];
    #pragma unroll
    for (int mt = 0; mt < 2; mt++)
        Abuf[0][mt] = *(const bf16x8*)(kbA + (mrow + mt * 16) * 32 + quad * 8);

    #pragma unroll
    for (int ks = 0; ks < NKS; ks++) {
        if (ks < NKS - 1) {
            #pragma unroll
            for (int mt = 0; mt < 2; mt++)
                Abuf[(ks + 1) & 1][mt] = *(const bf16x8*)(kbA + (ks + 1) * (O_ * 32) +
                                                          (mrow + mt * 16) * 32 + quad * 8);
        }
        int tap = ks >> 1;                     // compile-time after unroll
        int kh = tap / 3, kw = tap - kh * 3;
        int c0 = (ks & 1) * 32;
        const __bf16* Bb = xs + ((wj + kh) * 66 + kw + l15) * CPAD + c0 + quad * 8;
        #pragma unroll
        for (int nt = 0; nt < 4; nt++) {
            bf16x8 bfrag = *(const bf16x8*)(Bb + nt * 16 * CPAD);
            #pragma unroll
            for (int mt = 0; mt < 2; mt++)
                acc[mt][nt] = __builtin_amdgcn_mfma_f32_16x16x32_bf16(
                    Abuf[ks & 1][mt], bfrag, acc[mt][nt], 0, 0, 0);
        }
    }

    // epilogue: D row = quad*4 + reg, col = l15
    int h = h0 + wj;
    float* ob = out + ((size_t)b * O_ + wi * 32) * HW + h * W_;
    #pragma unroll
    for (int mt = 0; mt < 2; mt++) {
        #pragma unroll
        for (int nt = 0; nt < 4; nt++) {
            int w = nt * 16 + l15;
            #pragma unroll
            for (int r = 0; r < 4; r++) {
                int oo = mt * 16 + quad * 4 + r;
                ob[(size_t)oo * HW + w] = acc[mt][nt][r];
            }
        }
    }
}

// ---------------------------------------------------------------------------
// Launch (4 kernels)
// ---------------------------------------------------------------------------
extern "C" void kernel_launch(void* const* d_in, const int* in_sizes, int n_in,
                              void* d_out, int out_size, void* d_ws, size_t ws_size,
                              hipStream_t stream) {
    const float* x  = (const float*)d_in[0];
    const float* W1 = (const float*)d_in[1];
    const float* b1 = (const float*)d_in[2];
    const float* W2 = (const float*)d_in[3];
    const float* b2 = (const float*)d_in[4];
    const float* Wf = (const float*)d_in[5];
    const float* bf = (const float*)d_in[6];
    float* out = (float*)d_out;

    // Workspace layout:
    //   gap_part : 64*32*64 f32     @ 0         (512 KB)
    //   f2t      : 64*32 f32        @ 512 KB    (8 KB)
    //   kbf2     : 32*18*128*32 bf16 @ 528 KB   (4.72 MB)
    //   xT       : 32*64*64*64 bf16 @ ~5.25 MB  (16.8 MB)
    float*  gap_part = (float*)d_ws;
    float*  f2t      = (float*)((char*)d_ws + 524288);
    __bf16* kbf2     = (__bf16*)((char*)d_ws + 540672);
    __bf16* xT       = (__bf16*)((char*)d_ws + 540672 + (size_t)B_ * NKS * O_ * 32 * 2);

    transpose_gap<<<B_ * H_, 256, 0, stream>>>(x, xT, gap_part);
    mlp_kernel<<<B_, 64, 0, stream>>>(gap_part, W1, b1, W2, b2, f2t);
    kergen_kernel<<<256, 576, 0, stream>>>(f2t, Wf, bf, kbf2);
    conv_mfma<<<dim3(32, B_), 512, 0, stream>>>(xT, kbf2, out);
}

// Round 3
// 152.250 us; speedup vs baseline: 1.0095x; 1.0095x over previous
//
#include <hip/hip_runtime.h>

// Problem constants
#define B_  32
#define C_  64
#define H_  64
#define W_  64
#define O_  128
#define LAT 64
#define HW  (H_*W_)
#define KJ  (O_*C_*9)      // 73728
#define KTOT 576           // C_*9, GEMM K per batch
#define NKS 18             // K steps of 32

typedef __bf16 bf16x8 __attribute__((ext_vector_type(8)));
typedef float  f32x4  __attribute__((ext_vector_type(4)));

// ---------------------------------------------------------------------------
// Stage 1: transpose x -> xT[b][h][w][c] bf16, plus per-(b,h,c) row sums.
// ---------------------------------------------------------------------------
__global__ __launch_bounds__(256) void transpose_gap(const float* __restrict__ x,
                                                     __bf16* __restrict__ xT,
                                                     float* __restrict__ gap_part) {
    int bh = blockIdx.x, b = bh >> 6, h = bh & 63;
    __shared__ float lt[64 * 65];
    int t = threadIdx.x;
    int cc0 = t >> 4, w4 = (t & 15) * 4;

    #pragma unroll
    for (int i = 0; i < 4; i++) {
        int cc = cc0 + 16 * i;
        float4 v = *(const float4*)(x + (((size_t)(b * C_ + cc) * H_) + h) * W_ + w4);
        lt[cc * 65 + w4 + 0] = v.x;
        lt[cc * 65 + w4 + 1] = v.y;
        lt[cc * 65 + w4 + 2] = v.z;
        lt[cc * 65 + w4 + 3] = v.w;
        float s = (v.x + v.y) + (v.z + v.w);
        s += __shfl_xor(s, 1); s += __shfl_xor(s, 2);
        s += __shfl_xor(s, 4); s += __shfl_xor(s, 8);
        if ((t & 15) == 0) gap_part[h * 2048 + b * 64 + cc] = s;
    }
    __syncthreads();

    __bf16* dst = xT + ((size_t)(b * H_ + h) * W_) * C_;
    #pragma unroll
    for (int k = 0; k < 2; k++) {
        int chunk = t + k * 256;
        int w = chunk >> 3, c8 = chunk & 7;
        __bf16 g[8];
        #pragma unroll
        for (int i = 0; i < 8; i++) g[i] = (__bf16)lt[(c8 * 8 + i) * 65 + w];
        *(int4*)(dst + w * C_ + c8 * 8) = *(int4*)g;
    }
}

// ---------------------------------------------------------------------------
// Stage 2: gap reduction + MLP. Writes f2 TRANSPOSED: f2t[l][b] so kergen
// can read 16 consecutive per-b values with block-uniform s_loads.
// ---------------------------------------------------------------------------
__global__ __launch_bounds__(64) void mlp_kernel(const float* __restrict__ gap_part,
                                                 const float* __restrict__ W1,
                                                 const float* __restrict__ b1,
                                                 const float* __restrict__ W2,
                                                 const float* __restrict__ b2,
                                                 float* __restrict__ f2t) {
    int b = blockIdx.x, j = threadIdx.x;
    float s = 0.f;
    #pragma unroll 16
    for (int h = 0; h < 64; h++) s += gap_part[h * 2048 + b * 64 + j];
    __shared__ float g[LAT], f1[LAT];
    g[j] = s * (1.0f / (float)HW);
    __syncthreads();
    float acc = b1[j];
    #pragma unroll 8
    for (int l = 0; l < LAT; l++) acc = fmaf(g[l], W1[l * LAT + j], acc);
    f1[j] = fmaxf(acc, 0.f);
    __syncthreads();
    float acc2 = b2[j];
    #pragma unroll 8
    for (int l = 0; l < LAT; l++) acc2 = fmaf(f1[l], W2[l * LAT + j], acc2);
    f2t[j * B_ + b] = fmaxf(acc2, 0.f);       // transposed store
}

// ---------------------------------------------------------------------------
// Stage 3: kernel generator -> bf16, conv-native layout
//   kbf2[b][ks][o][kk],  ks = tap*2 + (c>=32), kk = c&31   (k = ks*32+kk)
// ---------------------------------------------------------------------------
#define KGP2 592
__global__ __launch_bounds__(576) void kergen_kernel(const float* __restrict__ f2t,
                                                     const float* __restrict__ Wf,
                                                     const float* __restrict__ bfv,
                                                     __bf16* __restrict__ kbf2) {
    int o = blockIdx.x & 127, b0 = (blockIdx.x >> 7) * 16;
    int t = threadIdx.x;
    __shared__ __bf16 ltk[16 * KGP2];          // 18.9 KB

    int j = o * KTOT + t;
    float acc[16];
    float base = bfv[j];
    #pragma unroll
    for (int i = 0; i < 16; i++) acc[i] = base;

    for (int l8 = 0; l8 < LAT; l8 += 8) {
        float w8[8];
        #pragma unroll
        for (int i = 0; i < 8; i++) w8[i] = Wf[(size_t)(l8 + i) * KJ + j];
        #pragma unroll
        for (int i = 0; i < 8; i++) {
            #pragma unroll
            for (int bb = 0; bb < 16; bb++)
                acc[bb] = fmaf(f2t[(l8 + i) * B_ + b0 + bb], w8[i], acc[bb]);
        }
    }

    int c = t / 9, tap = t - c * 9;
    int tpp = (tap * 2 + (c >> 5)) * 32 + (c & 31);
    #pragma unroll
    for (int bb = 0; bb < 16; bb++) ltk[bb * KGP2 + tpp] = (__bf16)acc[bb];
    __syncthreads();
    int ks = t >> 5, kk = t & 31;
    #pragma unroll
    for (int bb = 0; bb < 16; bb++)
        kbf2[(((size_t)(b0 + bb) * NKS + ks) * O_ + o) * 32 + kk] = ltk[bb * KGP2 + t];
}

// ---------------------------------------------------------------------------
// Stage 4: implicit-GEMM MFMA conv. M=128 o, N=128 px (2 rows), K=576.
// ROUND-3 CHANGES (keep round-2's spill-free 8-wave geometry):
// (a) b-major XCD swizzle. Old grid dim3(32,B_): linear id = bx+32*by,
//     32%8==0 -> XCD = bx%8 for EVERY b -> each XCD touched all 32 batches:
//     per-XCD L2 set = 4.7MB kbf2 + x slices >> 4MB -> A-loads were L2
//     MISSES (~900cy) that depth-1 prefetch (~40-80cy cover) never hid.
//     Now: 1-D grid 1024, xcd = n&7 owns 4 consecutive b (4x147KB A +
//     4x528KB xT = 2.7MB < 4MB L2), htile consecutive within b so halo
//     rows are L2/L1-local in time.
// (b) A-prefetch depth 1 -> 3 (Abuf[4][2] rotation, 32 VGPR): cover ~3
//     K-steps (~600cy wall at 4 waves/SIMD) >= L2-hit latency.
// Regs: 32 acc + 32 Abuf + ~16 bfrag + ~25 addr ~= 105 < 128 cap of
// (512,4) -> still no spill. LDS 75KB -> 2 blocks/CU, 16 waves.
// ---------------------------------------------------------------------------
#define CPAD 72
#define ROWE (66 * CPAD)

__global__ __launch_bounds__(512, 4) void conv_mfma(const __bf16* __restrict__ xT,
                                                    const __bf16* __restrict__ kbf2,
                                                    float* __restrict__ out) {
    int n   = blockIdx.x;                      // 0..1023
    int xcd = n & 7;
    int idx = n >> 3;                          // 0..127 within XCD
    int b   = xcd * 4 + (idx >> 5);            // 4 batches per XCD
    int htile = idx & 31;                      // consecutive h-tiles per b
    int h0 = htile * 2;
    __shared__ __bf16 xs[4 * ROWE];
    int tid = threadIdx.x;

    // zero halo columns w'=0 and w'=65
    if (tid < 64) {
        int r = tid >> 4, which = (tid >> 3) & 1, c8 = tid & 7;
        *(int4*)(xs + (r * 66 + which * 65) * CPAD + c8 * 8) = int4{0, 0, 0, 0};
    }
    // zero OOB rows (edge blocks only)
    if (h0 == 0) {
        for (int i = tid; i < ROWE / 8; i += 512)
            *(int4*)(xs + i * 8) = int4{0, 0, 0, 0};
    }
    if (h0 == H_ - 2) {
        for (int i = tid; i < ROWE / 8; i += 512)
            *(int4*)(xs + 3 * ROWE + i * 8) = int4{0, 0, 0, 0};
    }

    // stage rows h0-1 .. h0+2 (2048 int4 chunks over 512 threads)
    #pragma unroll
    for (int i = 0; i < 4; i++) {
        int chunk = tid + i * 512;
        int c8 = chunk & 7, w = (chunk >> 3) & 63, r = chunk >> 9;
        int hh = h0 - 1 + r;
        if ((unsigned)hh < (unsigned)H_) {
            int4 v = *(const int4*)(xT + ((size_t)(b * H_ + hh) * W_ + w) * C_ + c8 * 8);
            *(int4*)(xs + (r * 66 + w + 1) * CPAD + c8 * 8) = v;
        }
    }
    __syncthreads();

    int wave = tid >> 6, lane = tid & 63;
    int wi = wave >> 1, wj = wave & 1;         // wi: M 4x32, wj: h row
    int l15 = lane & 15, quad = lane >> 4;

    const __bf16* kbA = kbf2 + (size_t)b * (NKS * O_ * 32);
    int mrow = wi * 32 + l15;                  // +mt*16, mt<2

    f32x4 acc[2][4];
    #pragma unroll
    for (int mt = 0; mt < 2; mt++)
        #pragma unroll
        for (int nt = 0; nt < 4; nt++)
            acc[mt][nt] = (f32x4){0.f, 0.f, 0.f, 0.f};

    bf16x8 Abuf[4][2];
    #pragma unroll
    for (int d = 0; d < 3; d++)
        #pragma unroll
        for (int mt = 0; mt < 2; mt++)
            Abuf[d][mt] = *(const bf16x8*)(kbA + d * (O_ * 32) +
                                           (mrow + mt * 16) * 32 + quad * 8);

    #pragma unroll
    for (int ks = 0; ks < NKS; ks++) {
        if (ks < NKS - 3) {
            #pragma unroll
            for (int mt = 0; mt < 2; mt++)
                Abuf[(ks + 3) & 3][mt] = *(const bf16x8*)(kbA + (ks + 3) * (O_ * 32) +
                                                          (mrow + mt * 16) * 32 + quad * 8);
        }
        int tap = ks >> 1;                     // compile-time after unroll
        int kh = tap / 3, kw = tap - kh * 3;
        int c0 = (ks & 1) * 32;
        const __bf16* Bb = xs + ((wj + kh) * 66 + kw + l15) * CPAD + c0 + quad * 8;
        #pragma unroll
        for (int nt = 0; nt < 4; nt++) {
            bf16x8 bfrag = *(const bf16x8*)(Bb + nt * 16 * CPAD);
            #pragma unroll
            for (int mt = 0; mt < 2; mt++)
                acc[mt][nt] = __builtin_amdgcn_mfma_f32_16x16x32_bf16(
                    Abuf[ks & 3][mt], bfrag, acc[mt][nt], 0, 0, 0);
        }
    }

    // epilogue: D row = quad*4 + reg, col = l15
    int h = h0 + wj;
    float* ob = out + ((size_t)b * O_ + wi * 32) * HW + h * W_;
    #pragma unroll
    for (int mt = 0; mt < 2; mt++) {
        #pragma unroll
        for (int nt = 0; nt < 4; nt++) {
            int w = nt * 16 + l15;
            #pragma unroll
            for (int r = 0; r < 4; r++) {
                int oo = mt * 16 + quad * 4 + r;
                ob[(size_t)oo * HW + w] = acc[mt][nt][r];
            }
        }
    }
}

// ---------------------------------------------------------------------------
// Launch (4 kernels)
// ---------------------------------------------------------------------------
extern "C" void kernel_launch(void* const* d_in, const int* in_sizes, int n_in,
                              void* d_out, int out_size, void* d_ws, size_t ws_size,
                              hipStream_t stream) {
    const float* x  = (const float*)d_in[0];
    const float* W1 = (const float*)d_in[1];
    const float* b1 = (const float*)d_in[2];
    const float* W2 = (const float*)d_in[3];
    const float* b2 = (const float*)d_in[4];
    const float* Wf = (const float*)d_in[5];
    const float* bf = (const float*)d_in[6];
    float* out = (float*)d_out;

    // Workspace layout:
    //   gap_part : 64*32*64 f32     @ 0         (512 KB)
    //   f2t      : 64*32 f32        @ 512 KB    (8 KB)
    //   kbf2     : 32*18*128*32 bf16 @ 528 KB   (4.72 MB)
    //   xT       : 32*64*64*64 bf16 @ ~5.25 MB  (16.8 MB)
    float*  gap_part = (float*)d_ws;
    float*  f2t      = (float*)((char*)d_ws + 524288);
    __bf16* kbf2     = (__bf16*)((char*)d_ws + 540672);
    __bf16* xT       = (__bf16*)((char*)d_ws + 540672 + (size_t)B_ * NKS * O_ * 32 * 2);

    transpose_gap<<<B_ * H_, 256, 0, stream>>>(x, xT, gap_part);
    mlp_kernel<<<B_, 64, 0, stream>>>(gap_part, W1, b1, W2, b2, f2t);
    kergen_kernel<<<256, 576, 0, stream>>>(f2t, Wf, bf, kbf2);
    conv_mfma<<<1024, 512, 0, stream>>>(xT, kbf2, out);
}

// Round 4
// 151.163 us; speedup vs baseline: 1.0168x; 1.0072x over previous
//
#include <hip/hip_runtime.h>

// Problem constants
#define B_  32
#define C_  64
#define H_  64
#define W_  64
#define O_  128
#define LAT 64
#define HW  (H_*W_)
#define KJ  (O_*C_*9)      // 73728
#define KTOT 576           // C_*9, GEMM K per batch
#define NKS 18             // K steps of 32

typedef __bf16 bf16x8 __attribute__((ext_vector_type(8)));
typedef float  f32x4  __attribute__((ext_vector_type(4)));

// ---------------------------------------------------------------------------
// Stage 1: transpose x -> xT[b][h][w][c] bf16, plus per-(b,h,c) row sums.
// ---------------------------------------------------------------------------
__global__ __launch_bounds__(256) void transpose_gap(const float* __restrict__ x,
                                                     __bf16* __restrict__ xT,
                                                     float* __restrict__ gap_part) {
    int bh = blockIdx.x, b = bh >> 6, h = bh & 63;
    __shared__ float lt[64 * 65];
    int t = threadIdx.x;
    int cc0 = t >> 4, w4 = (t & 15) * 4;

    #pragma unroll
    for (int i = 0; i < 4; i++) {
        int cc = cc0 + 16 * i;
        float4 v = *(const float4*)(x + (((size_t)(b * C_ + cc) * H_) + h) * W_ + w4);
        lt[cc * 65 + w4 + 0] = v.x;
        lt[cc * 65 + w4 + 1] = v.y;
        lt[cc * 65 + w4 + 2] = v.z;
        lt[cc * 65 + w4 + 3] = v.w;
        float s = (v.x + v.y) + (v.z + v.w);
        s += __shfl_xor(s, 1); s += __shfl_xor(s, 2);
        s += __shfl_xor(s, 4); s += __shfl_xor(s, 8);
        if ((t & 15) == 0) gap_part[h * 2048 + b * 64 + cc] = s;
    }
    __syncthreads();

    __bf16* dst = xT + ((size_t)(b * H_ + h) * W_) * C_;
    #pragma unroll
    for (int k = 0; k < 2; k++) {
        int chunk = t + k * 256;
        int w = chunk >> 3, c8 = chunk & 7;
        __bf16 g[8];
        #pragma unroll
        for (int i = 0; i < 8; i++) g[i] = (__bf16)lt[(c8 * 8 + i) * 65 + w];
        *(int4*)(dst + w * C_ + c8 * 8) = *(int4*)g;
    }
}

// ---------------------------------------------------------------------------
// Stage 2: gap reduction + MLP. Writes f2 TRANSPOSED: f2t[l][b] so kergen
// can read 16 consecutive per-b values with block-uniform s_loads.
// ---------------------------------------------------------------------------
__global__ __launch_bounds__(64) void mlp_kernel(const float* __restrict__ gap_part,
                                                 const float* __restrict__ W1,
                                                 const float* __restrict__ b1,
                                                 const float* __restrict__ W2,
                                                 const float* __restrict__ b2,
                                                 float* __restrict__ f2t) {
    int b = blockIdx.x, j = threadIdx.x;
    float s = 0.f;
    #pragma unroll 16
    for (int h = 0; h < 64; h++) s += gap_part[h * 2048 + b * 64 + j];
    __shared__ float g[LAT], f1[LAT];
    g[j] = s * (1.0f / (float)HW);
    __syncthreads();
    float acc = b1[j];
    #pragma unroll 8
    for (int l = 0; l < LAT; l++) acc = fmaf(g[l], W1[l * LAT + j], acc);
    f1[j] = fmaxf(acc, 0.f);
    __syncthreads();
    float acc2 = b2[j];
    #pragma unroll 8
    for (int l = 0; l < LAT; l++) acc2 = fmaf(f1[l], W2[l * LAT + j], acc2);
    f2t[j * B_ + b] = fmaxf(acc2, 0.f);       // transposed store
}

// ---------------------------------------------------------------------------
// Stage 3: kernel generator -> bf16, conv-native layout
//   kbf2[b][ks][o][kk],  ks = tap*2 + (c>=32), kk = c&31   (k = ks*32+kk)
// ---------------------------------------------------------------------------
#define KGP2 592
__global__ __launch_bounds__(576) void kergen_kernel(const float* __restrict__ f2t,
                                                     const float* __restrict__ Wf,
                                                     const float* __restrict__ bfv,
                                                     __bf16* __restrict__ kbf2) {
    int o = blockIdx.x & 127, b0 = (blockIdx.x >> 7) * 16;
    int t = threadIdx.x;
    __shared__ __bf16 ltk[16 * KGP2];          // 18.9 KB

    int j = o * KTOT + t;
    float acc[16];
    float base = bfv[j];
    #pragma unroll
    for (int i = 0; i < 16; i++) acc[i] = base;

    for (int l8 = 0; l8 < LAT; l8 += 8) {
        float w8[8];
        #pragma unroll
        for (int i = 0; i < 8; i++) w8[i] = Wf[(size_t)(l8 + i) * KJ + j];
        #pragma unroll
        for (int i = 0; i < 8; i++) {
            #pragma unroll
            for (int bb = 0; bb < 16; bb++)
                acc[bb] = fmaf(f2t[(l8 + i) * B_ + b0 + bb], w8[i], acc[bb]);
        }
    }

    int c = t / 9, tap = t - c * 9;
    int tpp = (tap * 2 + (c >> 5)) * 32 + (c & 31);
    #pragma unroll
    for (int bb = 0; bb < 16; bb++) ltk[bb * KGP2 + tpp] = (__bf16)acc[bb];
    __syncthreads();
    int ks = t >> 5, kk = t & 31;
    #pragma unroll
    for (int bb = 0; bb < 16; bb++)
        kbf2[(((size_t)(b0 + bb) * NKS + ks) * O_ + o) * 32 + kk] = ltk[bb * KGP2 + t];
}

// ---------------------------------------------------------------------------
// Stage 4: implicit-GEMM MFMA conv. M=128 o, N=256 px (4 rows), K=576.
// ROUND-4 CHANGE. Per-CU floor arithmetic for the r2/r3 geometry:
//   MFMA 9.3us | LDS-read 11.5us (mt=2: each bfrag fed only 2 MFMA) |
//   L2-A 8.5us | HBM-out 10.2us; serial sum ~= 39.5us = measured ~40.
// r2's mt 4->2 halved B-reuse and DOUBLED the LDS floor - that canceled the
// occupancy gain. Fix: wave tile M64xN64 (wi in {0,1} M-half, wj in {0..3}
// h-row). Per K-step per wave: 4 afrag + 4 ds_read_b128 -> 16 MFMA:
// A-reuse 4 AND B-reuse 4. New LDS floor 5.8us.
// Regs: acc[4][4]=64 + afrag 16 + bfrag 16 + addr ~20 = ~116 < 128 cap of
// (512,4) -> no spill, NO explicit Abuf rotation (that's what pushed r1 over
// the cap); full unroll + 16 waves/CU TLP hide L2-hit A latency.
// LDS: 6 rows x 66 x 72 x 2B = 57KB -> 2 blocks/CU, grid 512 = exactly one
// generation. Halo amplification 2.0x -> 1.5x (6 staged rows feed 4).
// b-major XCD swizzle: each XCD owns 4 consecutive b (A+x set 2.7MB < 4MB).
// ---------------------------------------------------------------------------
#define CPAD 72
#define ROWE (66 * CPAD)

__global__ __launch_bounds__(512, 4) void conv_mfma(const __bf16* __restrict__ xT,
                                                    const __bf16* __restrict__ kbf2,
                                                    float* __restrict__ out) {
    int n   = blockIdx.x;                      // 0..511
    int xcd = n & 7;
    int idx = n >> 3;                          // 0..63 within XCD
    int b   = xcd * 4 + (idx >> 4);            // 4 batches per XCD
    int h0  = (idx & 15) * 4;                  // 4 output rows per block
    __shared__ __bf16 xs[6 * ROWE];            // 57 KB
    int tid = threadIdx.x;

    // zero halo columns w'=0 and w'=65 for all 6 staged rows
    if (tid < 96) {
        int r = tid >> 4, which = (tid >> 3) & 1, c8 = tid & 7;
        *(int4*)(xs + (r * 66 + which * 65) * CPAD + c8 * 8) = int4{0, 0, 0, 0};
    }
    // zero OOB rows (edge blocks only)
    if (h0 == 0) {
        for (int i = tid; i < ROWE / 8; i += 512)
            *(int4*)(xs + i * 8) = int4{0, 0, 0, 0};
    }
    if (h0 == H_ - 4) {
        for (int i = tid; i < ROWE / 8; i += 512)
            *(int4*)(xs + 5 * ROWE + i * 8) = int4{0, 0, 0, 0};
    }

    // stage rows h0-1 .. h0+4 (3072 int4 chunks over 512 threads)
    #pragma unroll
    for (int i = 0; i < 6; i++) {
        int c8 = tid & 7, w = (tid >> 3) & 63, r = i;
        int hh = h0 - 1 + r;
        if ((unsigned)hh < (unsigned)H_) {
            int4 v = *(const int4*)(xT + ((size_t)(b * H_ + hh) * W_ + w) * C_ + c8 * 8);
            *(int4*)(xs + (r * 66 + w + 1) * CPAD + c8 * 8) = v;
        }
    }
    __syncthreads();

    int wave = tid >> 6, lane = tid & 63;
    int wi = wave >> 2, wj = wave & 3;         // wi: M-half, wj: h-row 0..3
    int l15 = lane & 15, quad = lane >> 4;

    const __bf16* kbA = kbf2 + (size_t)b * (NKS * O_ * 32);
    int mrow = wi * 64 + l15;                  // +mt*16, mt<4

    f32x4 acc[4][4];
    #pragma unroll
    for (int mt = 0; mt < 4; mt++)
        #pragma unroll
        for (int nt = 0; nt < 4; nt++)
            acc[mt][nt] = (f32x4){0.f, 0.f, 0.f, 0.f};

    #pragma unroll
    for (int ks = 0; ks < NKS; ks++) {
        bf16x8 afrag[4];
        #pragma unroll
        for (int mt = 0; mt < 4; mt++)
            afrag[mt] = *(const bf16x8*)(kbA + ks * (O_ * 32) +
                                         (mrow + mt * 16) * 32 + quad * 8);
        int tap = ks >> 1;                     // compile-time after unroll
        int kh = tap / 3, kw = tap - kh * 3;
        int c0 = (ks & 1) * 32;
        const __bf16* Bb = xs + ((wj + kh) * 66 + kw + l15) * CPAD + c0 + quad * 8;
        #pragma unroll
        for (int nt = 0; nt < 4; nt++) {
            bf16x8 bfrag = *(const bf16x8*)(Bb + nt * 16 * CPAD);
            #pragma unroll
            for (int mt = 0; mt < 4; mt++)
                acc[mt][nt] = __builtin_amdgcn_mfma_f32_16x16x32_bf16(
                    afrag[mt], bfrag, acc[mt][nt], 0, 0, 0);
        }
    }

    // epilogue: D row = quad*4 + reg, col = l15
    int h = h0 + wj;
    float* ob = out + ((size_t)b * O_ + wi * 64) * HW + h * W_;
    #pragma unroll
    for (int mt = 0; mt < 4; mt++) {
        #pragma unroll
        for (int nt = 0; nt < 4; nt++) {
            int w = nt * 16 + l15;
            #pragma unroll
            for (int r = 0; r < 4; r++) {
                int oo = mt * 16 + quad * 4 + r;
                ob[(size_t)oo * HW + w] = acc[mt][nt][r];
            }
        }
    }
}

// ---------------------------------------------------------------------------
// Launch (4 kernels)
// ---------------------------------------------------------------------------
extern "C" void kernel_launch(void* const* d_in, const int* in_sizes, int n_in,
                              void* d_out, int out_size, void* d_ws, size_t ws_size,
                              hipStream_t stream) {
    const float* x  = (const float*)d_in[0];
    const float* W1 = (const float*)d_in[1];
    const float* b1 = (const float*)d_in[2];
    const float* W2 = (const float*)d_in[3];
    const float* b2 = (const float*)d_in[4];
    const float* Wf = (const float*)d_in[5];
    const float* bf = (const float*)d_in[6];
    float* out = (float*)d_out;

    // Workspace layout:
    //   gap_part : 64*32*64 f32     @ 0         (512 KB)
    //   f2t      : 64*32 f32        @ 512 KB    (8 KB)
    //   kbf2     : 32*18*128*32 bf16 @ 528 KB   (4.72 MB)
    //   xT       : 32*64*64*64 bf16 @ ~5.25 MB  (16.8 MB)
    float*  gap_part = (float*)d_ws;
    float*  f2t      = (float*)((char*)d_ws + 524288);
    __bf16* kbf2     = (__bf16*)((char*)d_ws + 540672);
    __bf16* xT       = (__bf16*)((char*)d_ws + 540672 + (size_t)B_ * NKS * O_ * 32 * 2);

    transpose_gap<<<B_ * H_, 256, 0, stream>>>(x, xT, gap_part);
    mlp_kernel<<<B_, 64, 0, stream>>>(gap_part, W1, b1, W2, b2, f2t);
    kergen_kernel<<<256, 576, 0, stream>>>(f2t, Wf, bf, kbf2);
    conv_mfma<<<512, 512, 0, stream>>>(xT, kbf2, out);
}

// Round 6
// 148.560 us; speedup vs baseline: 1.0346x; 1.0175x over previous
//
#include <hip/hip_runtime.h>

// Problem constants
#define B_  32
#define C_  64
#define H_  64
#define W_  64
#define O_  128
#define LAT 64
#define HW  (H_*W_)
#define KJ  (O_*C_*9)      // 73728
#define KTOT 576           // C_*9, GEMM K per batch
#define NKS 18             // K steps of 32
#define SLAB 4096          // bf16 elems per k-slab of kbf2 (O_*32)

typedef __bf16 bf16x8 __attribute__((ext_vector_type(8)));
typedef float  f32x4  __attribute__((ext_vector_type(4)));

// ---------------------------------------------------------------------------
// Stage 1: transpose x -> xT[b][h][w][c] bf16, plus per-(b,h,c) row sums.
// ---------------------------------------------------------------------------
__global__ __launch_bounds__(256) void transpose_gap(const float* __restrict__ x,
                                                     __bf16* __restrict__ xT,
                                                     float* __restrict__ gap_part) {
    int bh = blockIdx.x, b = bh >> 6, h = bh & 63;
    __shared__ float lt[64 * 65];
    int t = threadIdx.x;
    int cc0 = t >> 4, w4 = (t & 15) * 4;

    #pragma unroll
    for (int i = 0; i < 4; i++) {
        int cc = cc0 + 16 * i;
        float4 v = *(const float4*)(x + (((size_t)(b * C_ + cc) * H_) + h) * W_ + w4);
        lt[cc * 65 + w4 + 0] = v.x;
        lt[cc * 65 + w4 + 1] = v.y;
        lt[cc * 65 + w4 + 2] = v.z;
        lt[cc * 65 + w4 + 3] = v.w;
        float s = (v.x + v.y) + (v.z + v.w);
        s += __shfl_xor(s, 1); s += __shfl_xor(s, 2);
        s += __shfl_xor(s, 4); s += __shfl_xor(s, 8);
        if ((t & 15) == 0) gap_part[h * 2048 + b * 64 + cc] = s;
    }
    __syncthreads();

    __bf16* dst = xT + ((size_t)(b * H_ + h) * W_) * C_;
    #pragma unroll
    for (int k = 0; k < 2; k++) {
        int chunk = t + k * 256;
        int w = chunk >> 3, c8 = chunk & 7;
        __bf16 g[8];
        #pragma unroll
        for (int i = 0; i < 8; i++) g[i] = (__bf16)lt[(c8 * 8 + i) * 65 + w];
        *(int4*)(dst + w * C_ + c8 * 8) = *(int4*)g;
    }
}

// ---------------------------------------------------------------------------
// Stage 2: gap reduction + MLP. Writes f2 TRANSPOSED: f2t[l][b].
// ---------------------------------------------------------------------------
__global__ __launch_bounds__(64) void mlp_kernel(const float* __restrict__ gap_part,
                                                 const float* __restrict__ W1,
                                                 const float* __restrict__ b1,
                                                 const float* __restrict__ W2,
                                                 const float* __restrict__ b2,
                                                 float* __restrict__ f2t) {
    int b = blockIdx.x, j = threadIdx.x;
    float s = 0.f;
    #pragma unroll 16
    for (int h = 0; h < 64; h++) s += gap_part[h * 2048 + b * 64 + j];
    __shared__ float g[LAT], f1[LAT];
    g[j] = s * (1.0f / (float)HW);
    __syncthreads();
    float acc = b1[j];
    #pragma unroll 8
    for (int l = 0; l < LAT; l++) acc = fmaf(g[l], W1[l * LAT + j], acc);
    f1[j] = fmaxf(acc, 0.f);
    __syncthreads();
    float acc2 = b2[j];
    #pragma unroll 8
    for (int l = 0; l < LAT; l++) acc2 = fmaf(f1[l], W2[l * LAT + j], acc2);
    f2t[j * B_ + b] = fmaxf(acc2, 0.f);       // transposed store
}

// ---------------------------------------------------------------------------
// Stage 3: kernel generator -> bf16, FRAGMENT-LINEAR conv layout.
// kbf2 element (b, ks, o, kk) lives at
//   panel(b) + ks*4096 + (o>>4)*512 + (kk>>3)*128 + (o&15)*8 + (kk&7)
// This makes conv's A-fragment ds_read the optimal lane*16-contiguous
// pattern AND the 8KB k-slab a linear DMA target for global_load_lds
// (wave-uniform base + lane*16 — swizzle baked into the producer, rule 21).
// ---------------------------------------------------------------------------
#define KGP2 592
__global__ __launch_bounds__(576) void kergen_kernel(const float* __restrict__ f2t,
                                                     const float* __restrict__ Wf,
                                                     const float* __restrict__ bfv,
                                                     __bf16* __restrict__ kbf2) {
    int o = blockIdx.x & 127, b0 = (blockIdx.x >> 7) * 16;
    int t = threadIdx.x;
    __shared__ __bf16 ltk[16 * KGP2];          // 18.9 KB

    int j = o * KTOT + t;
    float acc[16];
    float base = bfv[j];
    #pragma unroll
    for (int i = 0; i < 16; i++) acc[i] = base;

    for (int l8 = 0; l8 < LAT; l8 += 8) {
        float w8[8];
        #pragma unroll
        for (int i = 0; i < 8; i++) w8[i] = Wf[(size_t)(l8 + i) * KJ + j];
        #pragma unroll
        for (int i = 0; i < 8; i++) {
            #pragma unroll
            for (int bb = 0; bb < 16; bb++)
                acc[bb] = fmaf(f2t[(l8 + i) * B_ + b0 + bb], w8[i], acc[bb]);
        }
    }

    int c = t / 9, tap = t - c * 9;
    int tpp = (tap * 2 + (c >> 5)) * 32 + (c & 31);
    #pragma unroll
    for (int bb = 0; bb < 16; bb++) ltk[bb * KGP2 + tpp] = (__bf16)acc[bb];
    __syncthreads();
    int ks = t >> 5, kk = t & 31;
    int OB = (o >> 6) * 4 + ((o >> 4) & 3);
    int OL = o & 15;
    size_t foff = (size_t)ks * SLAB + OB * 512 + (kk >> 3) * 128 + OL * 8 + (kk & 7);
    #pragma unroll
    for (int bb = 0; bb < 16; bb++)
        kbf2[(size_t)(b0 + bb) * (NKS * SLAB) + foff] = ltk[bb * KGP2 + t];
}

// ---------------------------------------------------------------------------
// Stage 4: implicit-GEMM MFMA conv. M=128 o, N=256 px (4 rows), K=576.
// A through LDS via async global_load_lds double-buffer.
// Diagnosis: r4's pipes all <= 11us (MFMA 9.3, LDS 5.8, L1-A 7.5, out 10.2)
// yet conv ~40us -> latency-bound: per ks every wave re-issues its A loads
// and eats 200-400cy L1/L2 latency (no reg headroom under the 128-cap to
// hoist; r0 counters: busy-sum ~25%). Fix with ZERO extra registers:
// per ks, all 512 threads issue ONE global_load_lds dwordx4 (8KB slab ks+1,
// linear dest), then ds_read A (lane*16 contiguous, conflict-free thanks to
// kergen's fragment-linear layout) + B, 16 MFMA, __syncthreads (its vmcnt
// drain sits a full K-step after the DMA issue -> latency covered).
// LDS: xs 57KB + Ab 2x8KB = 73.4KB -> still 2 blocks/CU, 16 waves.
// Regs ~110 (global-A addressing gone) < 128 cap -> no spill.
// ---------------------------------------------------------------------------
#define CPAD 72
#define ROWE (66 * CPAD)

__global__ __launch_bounds__(512, 4) void conv_mfma(const __bf16* __restrict__ xT,
                                                    const __bf16* __restrict__ kbf2,
                                                    float* __restrict__ out) {
    int n   = blockIdx.x;                      // 0..511
    int xcd = n & 7;
    int idx = n >> 3;                          // 0..63 within XCD
    int b   = xcd * 4 + (idx >> 4);            // 4 batches per XCD
    int h0  = (idx & 15) * 4;                  // 4 output rows per block
    __shared__ __bf16 xs[6 * ROWE];            // 57 KB
    __shared__ __bf16 Ab[2][SLAB];             // 16 KB A double-buffer
    int tid = threadIdx.x;

    const __bf16* kbA = kbf2 + (size_t)b * (NKS * SLAB);

    // prologue: DMA slab 0 into Ab[0] (lands before the staging barrier)
    __builtin_amdgcn_global_load_lds(
        reinterpret_cast<const unsigned int*>(kbA + tid * 8),
        reinterpret_cast<unsigned int*>(&Ab[0][(tid >> 6) * 512]), 16, 0, 0);

    // zero halo columns w'=0 and w'=65 for all 6 staged rows
    if (tid < 96) {
        int r = tid >> 4, which = (tid >> 3) & 1, c8 = tid & 7;
        *(int4*)(xs + (r * 66 + which * 65) * CPAD + c8 * 8) = int4{0, 0, 0, 0};
    }
    // zero OOB rows (edge blocks only)
    if (h0 == 0) {
        for (int i = tid; i < ROWE / 8; i += 512)
            *(int4*)(xs + i * 8) = int4{0, 0, 0, 0};
    }
    if (h0 == H_ - 4) {
        for (int i = tid; i < ROWE / 8; i += 512)
            *(int4*)(xs + 5 * ROWE + i * 8) = int4{0, 0, 0, 0};
    }

    // stage rows h0-1 .. h0+4
    #pragma unroll
    for (int i = 0; i < 6; i++) {
        int c8 = tid & 7, w = (tid >> 3) & 63, r = i;
        int hh = h0 - 1 + r;
        if ((unsigned)hh < (unsigned)H_) {
            int4 v = *(const int4*)(xT + ((size_t)(b * H_ + hh) * W_ + w) * C_ + c8 * 8);
            *(int4*)(xs + (r * 66 + w + 1) * CPAD + c8 * 8) = v;
        }
    }
    __syncthreads();                            // drains DMA(slab0) too

    int wave = tid >> 6, lane = tid & 63;
    int wi = wave >> 2, wj = wave & 3;         // wi: M-half, wj: h-row 0..3
    int l15 = lane & 15, quad = lane >> 4;

    f32x4 acc[4][4];
    #pragma unroll
    for (int mt = 0; mt < 4; mt++)
        #pragma unroll
        for (int nt = 0; nt < 4; nt++)
            acc[mt][nt] = (f32x4){0.f, 0.f, 0.f, 0.f};

    #pragma unroll
    for (int ks = 0; ks < NKS; ks++) {
        // issue next slab's DMA first: max separation from the drain
        if (ks < NKS - 1) {
            __builtin_amdgcn_global_load_lds(
                reinterpret_cast<const unsigned int*>(kbA + (ks + 1) * SLAB + tid * 8),
                reinterpret_cast<unsigned int*>(&Ab[(ks + 1) & 1][(tid >> 6) * 512]),
                16, 0, 0);
        }
        // A fragments: lane*16-contiguous ds_read_b128, conflict-free
        const __bf16* As = &Ab[ks & 1][(wi * 4) * 512 + lane * 8];
        bf16x8 afrag[4];
        #pragma unroll
        for (int mt = 0; mt < 4; mt++)
            afrag[mt] = *(const bf16x8*)(As + mt * 512);

        int tap = ks >> 1;                     // compile-time after unroll
        int kh = tap / 3, kw = tap - kh * 3;
        int c0 = (ks & 1) * 32;
        const __bf16* Bb = xs + ((wj + kh) * 66 + kw + l15) * CPAD + c0 + quad * 8;
        #pragma unroll
        for (int nt = 0; nt < 4; nt++) {
            bf16x8 bfrag = *(const bf16x8*)(Bb + nt * 16 * CPAD);
            #pragma unroll
            for (int mt = 0; mt < 4; mt++)
                acc[mt][nt] = __builtin_amdgcn_mfma_f32_16x16x32_bf16(
                    afrag[mt], bfrag, acc[mt][nt], 0, 0, 0);
        }
        if (ks < NKS - 1) __syncthreads();     // vmcnt drain: slab ks+1 ready
    }

    // epilogue: D row = quad*4 + reg, col = l15
    int h = h0 + wj;
    float* ob = out + ((size_t)b * O_ + wi * 64) * HW + h * W_;
    #pragma unroll
    for (int mt = 0; mt < 4; mt++) {
        #pragma unroll
        for (int nt = 0; nt < 4; nt++) {
            int w = nt * 16 + l15;
            #pragma unroll
            for (int r = 0; r < 4; r++) {
                int oo = mt * 16 + quad * 4 + r;
                ob[(size_t)oo * HW + w] = acc[mt][nt][r];
            }
        }
    }
}

// ---------------------------------------------------------------------------
// Launch (4 kernels)
// ---------------------------------------------------------------------------
extern "C" void kernel_launch(void* const* d_in, const int* in_sizes, int n_in,
                              void* d_out, int out_size, void* d_ws, size_t ws_size,
                              hipStream_t stream) {
    const float* x  = (const float*)d_in[0];
    const float* W1 = (const float*)d_in[1];
    const float* b1 = (const float*)d_in[2];
    const float* W2 = (const float*)d_in[3];
    const float* b2 = (const float*)d_in[4];
    const float* Wf = (const float*)d_in[5];
    const float* bf = (const float*)d_in[6];
    float* out = (float*)d_out;

    // Workspace layout:
    //   gap_part : 64*32*64 f32     @ 0         (512 KB)
    //   f2t      : 64*32 f32        @ 512 KB    (8 KB)
    //   kbf2     : 32*18*128*32 bf16 @ 528 KB   (4.72 MB)
    //   xT       : 32*64*64*64 bf16 @ ~5.25 MB  (16.8 MB)
    float*  gap_part = (float*)d_ws;
    float*  f2t      = (float*)((char*)d_ws + 524288);
    __bf16* kbf2     = (__bf16*)((char*)d_ws + 540672);
    __bf16* xT       = (__bf16*)((char*)d_ws + 540672 + (size_t)B_ * NKS * O_ * 32 * 2);

    transpose_gap<<<B_ * H_, 256, 0, stream>>>(x, xT, gap_part);
    mlp_kernel<<<B_, 64, 0, stream>>>(gap_part, W1, b1, W2, b2, f2t);
    kergen_kernel<<<256, 576, 0, stream>>>(f2t, Wf, bf, kbf2);
    conv_mfma<<<512, 512, 0, stream>>>(xT, kbf2, out);
}